// Round 1
// 184.153 us; speedup vs baseline: 1.0400x; 1.0400x over previous
//
#include <hip/hip_runtime.h>

#define UU 2048
#define DM 32
#define TB 128   // tile edge
#define NB 16    // batch
#define NP 3     // pairs
#define ASZ (NB * UU * DM)  // elements per split array = 1,048,576

// workspace layout (float offsets)
#define WS_S1 0
#define WS_S2 (NP * NB * UU)                 // 98304
#define WS_OO (2 * NP * NB * UU)             // 196608
#define WS_CCA (WS_OO + NP * NB * 2 * DM)    // 199680
#define WS_ZERO_F4 (WS_CCA / 4)              // 49920 float4 (S1,S2,OO zeroed)
#define WS_SPLIT 204800                      // ushort split arrays start here
// total ws bytes = 204800*4 + 6*ASZ*2 = 13,402,112 (~12.8 MB) — required.

typedef short short8_t __attribute__((ext_vector_type(8)));
typedef float float4_t __attribute__((ext_vector_type(4)));

#if __has_builtin(__builtin_amdgcn_exp2f)
#define EXP2(x) __builtin_amdgcn_exp2f(x)
#else
#define EXP2(x) exp2f(x)
#endif

// sqrt(log2(e)): scaling BOTH operands by this makes the MFMA dot equal
// log2(e) * (f1.f2), so exp(dot) == 2^(mfma result) — saves the per-element
// mul inside stage1's inner loop.
#define SQRT_LOG2E 1.2011224087864498f

__device__ inline void async16(void* lds, const void* g) {
  __builtin_amdgcn_global_load_lds(
      (const __attribute__((address_space(1))) unsigned int*)g,
      (__attribute__((address_space(3))) unsigned int*)lds, 16, 0, 0);
}

// split scaled x into bf16 hi (truncate) + bf16 lo (truncate of remainder).
__device__ inline void split8s(const float4 x0, const float4 x1, short8_t& h,
                               short8_t& lo) {
  float xs[8] = {x0.x, x0.y, x0.z, x0.w, x1.x, x1.y, x1.z, x1.w};
#pragma unroll
  for (int i = 0; i < 8; ++i) {
    float xv = xs[i] * SQRT_LOG2E;
    unsigned u = __float_as_uint(xv);
    h[i] = (short)(u >> 16);
    float hif = __uint_as_float(u & 0xffff0000u);
    lo[i] = (short)(__float_as_uint(xv - hif) >> 16);
  }
}

// ---------------------------------------------------------------------------
// Stage 0: one-time f32 -> (hi,lo) bf16 split of all three embeddings,
// scaled by sqrt(log2 e). Also zeroes the S1/S2/OO atomic accumulators
// (replaces the hipMemsetAsync dispatch).
// Layout: H + arr*2*ASZ = hi[16][2048][32], +ASZ = lo.  arr: 0=a 1=v 2=l.
// ---------------------------------------------------------------------------
__global__ __launch_bounds__(256) void stage0_prep(
    const float* __restrict__ a, const float* __restrict__ v,
    const float* __restrict__ l, float* __restrict__ ws) {
  const int gid = blockIdx.x * 256 + threadIdx.x;  // 0..393215
  if (gid < WS_ZERO_F4) ((float4*)ws)[gid] = make_float4(0.f, 0.f, 0.f, 0.f);

  const int per = ASZ / 8;  // 131072 threads per input array
  const int arr = (gid >= per) + (gid >= 2 * per);  // uniform per block
  const float* src = (arr == 0) ? a : (arr == 1) ? v : l;
  const int loc = gid - arr * per;
  const float4* sp = (const float4*)(src + (size_t)loc * 8);
  float4 x0 = sp[0], x1 = sp[1];
  short8_t h, lo;
  split8s(x0, x1, h, lo);
  unsigned short* hq =
      (unsigned short*)(ws + WS_SPLIT) + (size_t)arr * 2 * ASZ + (size_t)loc * 8;
  *(short8_t*)hq = h;
  *(short8_t*)(hq + ASZ) = lo;
}

// ---------------------------------------------------------------------------
// Stage 1 (MFMA bf16x3): for each (pair, b) compute
//   S1[j] = sum_i 2^(g1_i . g2_j),  S2[i] = sum_j 2^(g1_i . g2_j)
// where g = sqrt(log2e)*f, so 2^dot == exp(f1.f2).
// 128x128 tile/block, 4 waves; wave w covers rows [w*32, w*32+32).
// B tile: global_load_lds width-16 into linear [128][32] LDS (64-B rows:
// the (lm,lq) b128 fragment read hits every bank exactly 8x -> conflict-free).
// A fragments: direct global->VGPR (permuted-contiguous 1KB per inst).
// XCD swizzle: 6 consecutive (p,b) per XCD -> 512 KB bf16 set, L2-resident.
// C/D layout: col=lane&15, row=(lane>>4)*4+reg  [m89-verified].
// ---------------------------------------------------------------------------
__global__ __launch_bounds__(256, 4) void stage1_sums(
    const unsigned short* __restrict__ H, float* __restrict__ S1,
    float* __restrict__ S2) {
  // bijective XCD swizzle of the 12288-block grid (12288 % 8 == 0)
  const int lid = blockIdx.x;
  const int xcd = lid & 7;
  const int q = lid >> 3;            // 0..1535
  const int z = xcd * 6 + (q >> 8);  // 0..47  (p*16+b)
  const int tidx = q & 255;
  const int p = z >> 4, b = z & 15;
  const int i0 = (tidx >> 4) * TB;
  const int j0 = (tidx & 15) * TB;

  const int a1 = (p == 2) ? 1 : 0;  // p0:(a,v) p1:(a,l) p2:(v,l)
  const int a2 = (p == 0) ? 1 : 2;
  const unsigned short* f1h = H + (size_t)a1 * 2 * ASZ + (size_t)b * UU * DM;
  const unsigned short* f2h = H + (size_t)a2 * 2 * ASZ + (size_t)b * UU * DM;

  __shared__ __align__(16) unsigned short Bh[TB][DM];
  __shared__ __align__(16) unsigned short Bl[TB][DM];
  __shared__ float ldsC[4][TB];

  const int t = threadIdx.x;
  const int lane = t & 63, w = t >> 6;

  // B staging: wave w stages rows [w*32, w*32+32) of hi and lo.
  {
    const unsigned short* gh = f2h + (size_t)(j0 + w * 32) * DM + lane * 8;
    async16(&Bh[w * 32][0], gh);
    async16(&Bh[w * 32 + 16][0], gh + 16 * DM);
    const unsigned short* gl = gh + ASZ;
    async16(&Bl[w * 32][0], gl);
    async16(&Bl[w * 32 + 16][0], gl + 16 * DM);
  }

  const int lm = lane & 15, lq = lane >> 4, k0 = lq * 8;

  // A fragments straight from global (wave-private rows).
  short8_t a_h[2], a_l[2];
  {
    const unsigned short* ar = f1h + (size_t)(i0 + w * 32 + lm) * DM + k0;
#pragma unroll
    for (int rt = 0; rt < 2; ++rt) {
      a_h[rt] = *(const short8_t*)(ar + rt * 16 * DM);
      a_l[rt] = *(const short8_t*)(ar + ASZ + rt * 16 * DM);
    }
  }
  __syncthreads();  // drains vmcnt -> B tiles visible

  float rowp[2][4];
  float colp[8];
#pragma unroll
  for (int rt = 0; rt < 2; ++rt)
#pragma unroll
    for (int r = 0; r < 4; ++r) rowp[rt][r] = 0.f;
#pragma unroll
  for (int ct = 0; ct < 8; ++ct) colp[ct] = 0.f;

#pragma unroll
  for (int ct = 0; ct < 8; ++ct) {
    short8_t b_h = *(const short8_t*)&Bh[ct * 16 + lm][k0];
    short8_t b_l = *(const short8_t*)&Bl[ct * 16 + lm][k0];
#pragma unroll
    for (int rt = 0; rt < 2; ++rt) {
      float4_t c = {0.f, 0.f, 0.f, 0.f};
      c = __builtin_amdgcn_mfma_f32_16x16x32_bf16(a_h[rt], b_h, c, 0, 0, 0);
      c = __builtin_amdgcn_mfma_f32_16x16x32_bf16(a_h[rt], b_l, c, 0, 0, 0);
      c = __builtin_amdgcn_mfma_f32_16x16x32_bf16(a_l[rt], b_h, c, 0, 0, 0);
      float e0 = EXP2(c[0]);
      float e1 = EXP2(c[1]);
      float e2 = EXP2(c[2]);
      float e3 = EXP2(c[3]);
      rowp[rt][0] += e0;
      rowp[rt][1] += e1;
      rowp[rt][2] += e2;
      rowp[rt][3] += e3;
      colp[ct] += (e0 + e1) + (e2 + e3);
    }
  }

  const size_t base = (size_t)(p * NB + b) * UU;

  // Row (i) sums: reduce across the 16 lanes of each quarter
#pragma unroll
  for (int rt = 0; rt < 2; ++rt)
#pragma unroll
    for (int r = 0; r < 4; ++r) {
      float vv = rowp[rt][r];
      vv += __shfl_xor(vv, 1, 64);
      vv += __shfl_xor(vv, 2, 64);
      vv += __shfl_xor(vv, 4, 64);
      vv += __shfl_xor(vv, 8, 64);
      if (lm == 0)
        atomicAdd(&S2[base + i0 + w * 32 + rt * 16 + lq * 4 + r], vv);
    }

  // Col (j) sums: reduce across quarters, then across waves via LDS
#pragma unroll
  for (int ct = 0; ct < 8; ++ct) {
    float vv = colp[ct];
    vv += __shfl_xor(vv, 16, 64);
    vv += __shfl_xor(vv, 32, 64);
    if (lane < 16) ldsC[w][ct * 16 + lane] = vv;
  }
  __syncthreads();
  if (t < TB) {
    float s = ldsC[0][t] + ldsC[1][t] + ldsC[2][t] + ldsC[3][t];
    atomicAdd(&S1[base + j0 + t], s);
  }
}

// ---------------------------------------------------------------------------
// Stage 2: per (pair, b, dir, chunk-of-256-rows) accumulate the 32-vector
//   dir0: O1 += sum_j exp(f1_0 . f2_j)/S1[j] * f2_j
//   dir1: O2 += sum_i exp(f1_i . f2_0)/S2[i] * f1_i
// Two-phase: (1) each thread = one row: dot, w=exp/den -> LDS (row also
// staged to LDS, pad-36 stride = conflict-free); (2) thread (slice,dim)
// re-accumulates 32 rows from LDS. Replaces the 192 shfl_down per thread.
// ---------------------------------------------------------------------------
__global__ __launch_bounds__(256) void stage2_O(
    const float* __restrict__ a, const float* __restrict__ v,
    const float* __restrict__ l, const float* __restrict__ S1,
    const float* __restrict__ S2, float* __restrict__ OO) {
  const int idx = blockIdx.x;
  const int chunk = idx & 7;
  const int pd = idx >> 3;
  const int dir = pd & 1;
  const int pb = pd >> 1;
  const int p = pb >> 4, b = pb & 15;
  const float* f1 = (p == 2) ? v : a;
  const float* f2 = (p == 0) ? v : l;
  f1 += (size_t)b * UU * DM;
  f2 += (size_t)b * UU * DM;
  const float* qrow = (dir == 0) ? f1 : f2;
  const float* rows = (dir == 0) ? f2 : f1;
  const float* den = ((dir == 0) ? S1 : S2) + (size_t)pb * UU;

  __shared__ float qv[DM];
  __shared__ __align__(16) float rowsL[256 * 36];  // pad 36 -> bank-free
  __shared__ float wL[256];
  __shared__ float wred[8][DM];
  const int t = threadIdx.x;
  if (t < DM) qv[t] = qrow[t];
  __syncthreads();

  const int r = chunk * 256 + t;
  const float4* rp = (const float4*)(rows + (size_t)r * DM);
  float dot = 0.f;
#pragma unroll
  for (int qq = 0; qq < 8; ++qq) {
    float4 x = rp[qq];
    *(float4*)&rowsL[t * 36 + qq * 4] = x;
    dot = fmaf(x.x, qv[4 * qq + 0], dot);
    dot = fmaf(x.y, qv[4 * qq + 1], dot);
    dot = fmaf(x.z, qv[4 * qq + 2], dot);
    dot = fmaf(x.w, qv[4 * qq + 3], dot);
  }
  wL[t] = __expf(dot) / den[r];
  __syncthreads();

  const int d = t & 31, sl = t >> 5;
  float acc = 0.f;
#pragma unroll
  for (int k = 0; k < 32; ++k) {
    const int rr = sl * 32 + k;
    acc = fmaf(wL[rr], rowsL[rr * 36 + d], acc);
  }
  wred[sl][d] = acc;
  __syncthreads();
  if (t < DM) {
    float o = 0.f;
#pragma unroll
    for (int s2 = 0; s2 < 8; ++s2) o += wred[s2][t];
    atomicAdd(&OO[(size_t)pd * DM + t], o);
  }
}

// ---------------------------------------------------------------------------
// Stage 3 (1024 threads, one block):
//   Bi[b][p][dir*32+d] = OO[(p*16+b)*2+dir][d] * qrow[d]
//   Ci = tanh(Bi@fc1^T + fc1_b)@fc2^T ; alpha = softmax over batch;
//   CCA[b,:] = sum_k alpha[b,k] * Bi[b,k,:]
// fc1w staged into pad-65 LDS (kills the 64-line global gather per fma).
// ---------------------------------------------------------------------------
__global__ __launch_bounds__(1024) void stage3_head(
    const float* __restrict__ a, const float* __restrict__ v,
    const float* __restrict__ l, const float* __restrict__ OO,
    const float* __restrict__ fc1w, const float* __restrict__ fc1b,
    const float* __restrict__ fc2w, float* __restrict__ CCA) {
  const int t = threadIdx.x;
  __shared__ float BiL[NB * NP * 64];
  __shared__ float CiS[NB * NP];
  __shared__ float denomk[NP];
  __shared__ float fwL[64 * 65];

  // stage fc1w (64x64)
#pragma unroll
  for (int it = 0; it < 4; ++it) {
    int m = it * 1024 + t;
    fwL[(m >> 6) * 65 + (m & 63)] = fc1w[m];
  }

  // Phase A: Bi = OO * qrow
#pragma unroll
  for (int iter = 0; iter < 3; ++iter) {
    int m = iter * 1024 + t;  // 0..3071
    int bk = m >> 6;          // b*NP + p
    int h = m & 63;
    int b = bk / NP, p = bk - b * NP;
    int dir = h >> 5, hd = h & 31;
    const float* base = (dir == 0) ? ((p == 2) ? v : a) : ((p == 0) ? v : l);
    float q = base[(size_t)b * UU * DM + hd];
    int pb = p * NB + b;
    BiL[bk * 64 + h] = OO[(pb * 2 + dir) * DM + hd] * q;
  }
  __syncthreads();

  // Phase B: Ci[bk]; wave g handles bk = g + 16*iter
  const int h = t & 63;
  const int g = t >> 6;  // 0..15
#pragma unroll
  for (int iter = 0; iter < 3; ++iter) {
    int bk = g + 16 * iter;
    float x = fc1b[h];
#pragma unroll 8
    for (int c = 0; c < 64; ++c)
      x = fmaf(BiL[bk * 64 + c], fwL[h * 65 + c], x);
    float vv = tanhf(x) * fc2w[h];
#pragma unroll
    for (int off = 32; off > 0; off >>= 1) vv += __shfl_down(vv, off, 64);
    if (h == 0) CiS[bk] = vv;
  }
  __syncthreads();

  if (t < NP) {
    float s = 0.f;
    for (int b = 0; b < NB; ++b) s += __expf(CiS[b * NP + t]);
    denomk[t] = s;
  }
  __syncthreads();

  // Phase C: CCA[b*64+h]
  {
    int b = g;
    float s = 0.f;
#pragma unroll
    for (int k = 0; k < NP; ++k)
      s += __expf(CiS[b * NP + k]) / denomk[k] * BiL[(b * NP + k) * 64 + h];
    CCA[b * 64 + h] = s;
  }
}

// ---------------------------------------------------------------------------
// Stage 4: broadcast CCA[b,:] to out[b, u, :] for all u.  float4 stores.
// ---------------------------------------------------------------------------
__global__ __launch_bounds__(256) void stage4_bcast(
    const float* __restrict__ CCA, float4* __restrict__ out) {
  const int gid = blockIdx.x * 256 + threadIdx.x;  // 0 .. 524287
  const int c4 = gid & 15;
  const int b = gid >> 15;
  const float4* cc = (const float4*)CCA;
  out[gid] = cc[b * 16 + c4];
}

extern "C" void kernel_launch(void* const* d_in, const int* in_sizes, int n_in,
                              void* d_out, int out_size, void* d_ws,
                              size_t ws_size, hipStream_t stream) {
  const float* a = (const float*)d_in[0];
  const float* v = (const float*)d_in[1];
  const float* l = (const float*)d_in[2];
  const float* fc1w = (const float*)d_in[3];
  const float* fc1b = (const float*)d_in[4];
  const float* fc2w = (const float*)d_in[5];
  float* out = (float*)d_out;

  float* ws = (float*)d_ws;
  float* S1 = ws + WS_S1;
  float* S2 = ws + WS_S2;
  float* OO = ws + WS_OO;
  float* CCA = ws + WS_CCA;
  const unsigned short* H = (const unsigned short*)(ws + WS_SPLIT);

  stage0_prep<<<dim3(1536), 256, 0, stream>>>(a, v, l, ws);
  stage1_sums<<<dim3(12288), 256, 0, stream>>>(H, S1, S2);
  stage2_O<<<dim3(NP * NB * 2 * 8), 256, 0, stream>>>(a, v, l, S1, S2, OO);
  stage3_head<<<dim3(1), 1024, 0, stream>>>(a, v, l, OO, fc1w, fc1b, fc2w,
                                            CCA);
  stage4_bcast<<<dim3(2048), 256, 0, stream>>>(CCA, (float4*)out);
}